// Round 1
// baseline (531.857 us; speedup 1.0000x reference)
//
#include <hip/hip_runtime.h>
#include <math.h>
#include <stdint.h>

// ---- static hash-grid config (mirrors the reference) ----
// RES[l] = 16 << l, l = 0..9
// TSIZE  = {4920, 35944, 274632, 2097152 x7}
// levels 0..2 dense ((res+1)^3 <= TSIZE), levels 3..9 hashed (TSIZE = 2^21)
__constant__ int c_offset[10] = {0, 4920, 40864, 315496, 2412648,
                                 4509800, 6606952, 8704104, 10801256, 12898408};

#define NSAMP 64

// ---------------------------------------------------------------------------
// Kernel 1: contract + hash-grid encode + erf-weighted mean over samples.
// One block per ray. 256 threads = 64 samples x 4 level-groups
// (wave g handles levels l = g, g+4, g+8). Wave-aligned shuffle reduction.
// ---------------------------------------------------------------------------
__global__ __launch_bounds__(256) void k_encode(
    const float* __restrict__ means, const float* __restrict__ stds,
    const float* __restrict__ table, float* __restrict__ feats_ws,
    float* __restrict__ coord_out)
{
    const int b = blockIdx.x;
    const int t = threadIdx.x;
    const int n = t & 63;   // sample
    const int g = t >> 6;   // level group 0..3 (== wave id)

    // ---- load sample, contract ----
    const float* mp = means + ((size_t)b * NSAMP + n) * 3;
    float mx = mp[0], my = mp[1], mz = mp[2];
    float sd = stds[(size_t)b * NSAMP + n];

    float msq = fmaxf(mx * mx + my * my + mz * mz, 1.1920929e-7f);
    float mag = sqrtf(msq);
    float scl = (2.0f * mag - 1.0f) / msq;
    bool inside = (msq <= 1.0f);
    float zx, zy, zz, det13;
    if (inside) { zx = mx; zy = my; zz = mz; det13 = 1.0f; }
    else        { zx = mx * scl; zy = my * scl; zz = mz * scl;
                  det13 = cbrtf(scl * scl / msq); }
    sd = sd * det13 * 0.5f;           // std * det^(1/3), then /2 (bound=2)
    zx *= 0.5f; zy *= 0.5f; zz *= 0.5f;

    // encoder input in [0,1]
    float ux = fminf(fmaxf((zx + 1.0f) * 0.5f, 0.0f), 1.0f);
    float uy = fminf(fmaxf((zy + 1.0f) * 0.5f, 0.0f), 1.0f);
    float uz = fminf(fmaxf((zz + 1.0f) * 0.5f, 0.0f), 1.0f);

    float acc[12];                    // up to 3 levels * 4 dims, erf-weighted
    #pragma unroll
    for (int i = 0; i < 12; ++i) acc[i] = 0.0f;

    int li = 0;
    for (int l = g; l < 10; l += 4, ++li) {
        const int   res = 16 << l;
        const float rf  = (float)res;
        float px = ux * (rf - 1.0f) + 0.5f;
        float py = uy * (rf - 1.0f) + 0.5f;
        float pz = uz * (rf - 1.0f) + 0.5f;
        float pgx = floorf(px), pgy = floorf(py), pgz = floorf(pz);
        float fx = px - pgx, fy = py - pgy, fz = pz - pgz;
        uint32_t cx = (uint32_t)pgx, cy = (uint32_t)pgy, cz = (uint32_t)pgz;

        const float* tb = table + (size_t)c_offset[l] * 4;

        uint32_t idx[8];
        if (l < 3) {                       // dense tiled level
            uint32_t s = (uint32_t)res + 1u;
            #pragma unroll
            for (int ci = 0; ci < 8; ++ci) {
                uint32_t X = cx + ((ci >> 2) & 1u);
                uint32_t Y = cy + ((ci >> 1) & 1u);
                uint32_t Z = cz + (ci & 1u);
                idx[ci] = X + s * Y + s * s * Z;
            }
        } else {                           // hashed level, TSIZE = 2^21
            #pragma unroll
            for (int ci = 0; ci < 8; ++ci) {
                uint32_t X = cx + ((ci >> 2) & 1u);
                uint32_t Y = cy + ((ci >> 1) & 1u);
                uint32_t Z = cz + (ci & 1u);
                idx[ci] = (X ^ (Y * 2654435761u) ^ (Z * 805459861u)) & 0x1FFFFFu;
            }
        }

        // 8 independent 16B gathers in flight
        float4 f[8];
        #pragma unroll
        for (int ci = 0; ci < 8; ++ci)
            f[ci] = *(const float4*)(tb + (size_t)idx[ci] * 4);

        float gx0 = 1.0f - fx, gy0 = 1.0f - fy, gz0 = 1.0f - fz;
        float w[8];
        w[0] = gx0 * gy0 * gz0; w[1] = gx0 * gy0 * fz;
        w[2] = gx0 * fy  * gz0; w[3] = gx0 * fy  * fz;
        w[4] = fx  * gy0 * gz0; w[5] = fx  * gy0 * fz;
        w[6] = fx  * fy  * gz0; w[7] = fx  * fy  * fz;

        float f0 = 0.f, f1 = 0.f, f2 = 0.f, f3 = 0.f;
        #pragma unroll
        for (int ci = 0; ci < 8; ++ci) {
            f0 += w[ci] * f[ci].x; f1 += w[ci] * f[ci].y;
            f2 += w[ci] * f[ci].z; f3 += w[ci] * f[ci].w;
        }

        // erf multiscale weight: erf(1/sqrt(8*std^2*res^2)), std,res > 0
        float wl = erff(1.0f / (2.8284271247461903f * sd * rf));
        acc[li * 4 + 0] = f0 * wl; acc[li * 4 + 1] = f1 * wl;
        acc[li * 4 + 2] = f2 * wl; acc[li * 4 + 3] = f3 * wl;
    }

    // ---- wave reduction over the 64 samples (wave == level group) ----
    #pragma unroll
    for (int i = 0; i < 12; ++i) {
        float v = acc[i];
        #pragma unroll
        for (int off = 32; off > 0; off >>= 1) v += __shfl_down(v, off, 64);
        acc[i] = v;
    }
    if (n == 0) {
        int lj = 0;
        for (int l = g; l < 10; l += 4, ++lj) {
            #pragma unroll
            for (int d = 0; d < 4; ++d)
                feats_ws[(size_t)b * 40 + l * 4 + d] =
                    acc[lj * 4 + d] * (1.0f / 64.0f);
        }
    }

    // coord = mean over samples of contracted/2 means (wave 0 only)
    if (g == 0) {
        float v0 = zx, v1 = zy, v2 = zz;
        #pragma unroll
        for (int off = 32; off > 0; off >>= 1) {
            v0 += __shfl_down(v0, off, 64);
            v1 += __shfl_down(v1, off, 64);
            v2 += __shfl_down(v2, off, 64);
        }
        if (n == 0) {
            coord_out[(size_t)b * 3 + 0] = v0 * (1.0f / 64.0f);
            coord_out[(size_t)b * 3 + 1] = v1 * (1.0f / 64.0f);
            coord_out[(size_t)b * 3 + 2] = v2 * (1.0f / 64.0f);
        }
    }
}

// ---------------------------------------------------------------------------
// Kernel 2: per-ray MLP chain. One block (128 threads) per ray;
// thread j computes neuron j of each layer; activations staged in LDS.
// ---------------------------------------------------------------------------
__global__ __launch_bounds__(128) void k_mlp(
    const float* __restrict__ feats, const float* __restrict__ viewdirs,
    const float* __restrict__ w_d1, const float* __restrict__ b_d1,
    const float* __restrict__ w_d2, const float* __restrict__ b_d2,
    const float* __restrict__ w_v0, const float* __restrict__ b_v0,
    const float* __restrict__ w_v1, const float* __restrict__ b_v1,
    const float* __restrict__ w_rgb, const float* __restrict__ b_rgb,
    float* __restrict__ dens_out, float* __restrict__ rgb_out)
{
    const int b = blockIdx.x;
    const int t = threadIdx.x;

    __shared__ float sf[40];     // hash feats
    __shared__ float sh1[64];    // density_layer[0] out
    __shared__ float sx[155];    // bottleneck x[128] ++ dir_enc[27] == "inputs"
    __shared__ float sh2[128];   // lin_second_stage_0 out
    __shared__ float sh4[128];   // lin_second_stage_1 out

    if (t < 40) sf[t] = feats[(size_t)b * 40 + t];

    // dir_enc = [vd, sin(vd*2^i), cos(vd*2^i)]  (i = 0..3) -> 27 dims
    if (t >= 64 && t < 64 + 27) {
        int k = t - 64;
        const float* vd = viewdirs + (size_t)b * 3;
        float v;
        if (k < 3) {
            v = vd[k];
        } else if (k < 15) {
            int j = k - 3;  float sc = (float)(1 << (j / 3));
            v = sinf(vd[j % 3] * sc);
        } else {
            int j = k - 15; float sc = (float)(1 << (j / 3));
            v = cosf(vd[j % 3] * sc);   // sin(x + pi/2)
        }
        sx[128 + k] = v;
    }
    __syncthreads();

    // density_layer[0]: 40 -> 64, relu
    if (t < 64) {
        float a = b_d1[t];
        #pragma unroll 8
        for (int i = 0; i < 40; ++i) a += sf[i] * w_d1[i * 64 + t];
        sh1[t] = fmaxf(a, 0.0f);
    }
    __syncthreads();

    // density_layer[2]: 64 -> 128 (no relu) => bottleneck x
    {
        float a = b_d2[t];
        #pragma unroll 8
        for (int i = 0; i < 64; ++i) a += sh1[i] * w_d2[i * 128 + t];
        sx[t] = a;
    }
    __syncthreads();

    // density = softplus(x[0] - 1)  (stable logaddexp(x,0))
    if (t == 0) {
        float rd = sx[0] - 1.0f;
        dens_out[b] = fmaxf(rd, 0.0f) + log1pf(expf(-fabsf(rd)));
    }

    // lin_second_stage_0: 155 -> 128, relu
    {
        float a = b_v0[t];
        #pragma unroll 8
        for (int i = 0; i < 155; ++i) a += sx[i] * w_v0[i * 128 + t];
        sh2[t] = fmaxf(a, 0.0f);
    }
    __syncthreads();

    // lin_second_stage_1: concat(h2, inputs) [283] -> 128, relu
    {
        float a = b_v1[t];
        #pragma unroll 8
        for (int i = 0; i < 128; ++i) a += sh2[i] * w_v1[i * 128 + t];
        #pragma unroll 8
        for (int i = 0; i < 155; ++i) a += sx[i] * w_v1[(128 + i) * 128 + t];
        sh4[t] = fmaxf(a, 0.0f);
    }
    __syncthreads();

    // rgb head: 128 -> 3, sigmoid, pad
    if (t < 3) {
        float a = b_rgb[t];
        #pragma unroll 8
        for (int i = 0; i < 128; ++i) a += sh4[i] * w_rgb[i * 3 + t];
        float s = 1.0f / (1.0f + expf(-a));
        rgb_out[(size_t)b * 3 + t] = s * 1.002f - 0.001f;
    }
}

// ---------------------------------------------------------------------------
extern "C" void kernel_launch(void* const* d_in, const int* in_sizes, int n_in,
                              void* d_out, int out_size, void* d_ws, size_t ws_size,
                              hipStream_t stream)
{
    // setup_inputs order:
    // 0 rand, 1 means, 2 stds, 3 viewdirs, 4 table,
    // 5 w_d1, 6 b_d1, 7 w_d2, 8 b_d2, 9 w_v0, 10 b_v0,
    // 11 w_v1, 12 b_v1, 13 w_rgb, 14 b_rgb
    const float* means    = (const float*)d_in[1];
    const float* stds     = (const float*)d_in[2];
    const float* viewdirs = (const float*)d_in[3];
    const float* table    = (const float*)d_in[4];
    const float* w_d1  = (const float*)d_in[5];
    const float* b_d1  = (const float*)d_in[6];
    const float* w_d2  = (const float*)d_in[7];
    const float* b_d2  = (const float*)d_in[8];
    const float* w_v0  = (const float*)d_in[9];
    const float* b_v0  = (const float*)d_in[10];
    const float* w_v1  = (const float*)d_in[11];
    const float* b_v1  = (const float*)d_in[12];
    const float* w_rgb = (const float*)d_in[13];
    const float* b_rgb = (const float*)d_in[14];

    const int B = in_sizes[2] / NSAMP;   // stds is [B, 64]

    float* out   = (float*)d_out;
    float* coord = out;                  // [B,3]
    float* dens  = out + (size_t)B * 3;  // [B]
    float* rgb   = out + (size_t)B * 4;  // [B,3]

    float* feats_ws = (float*)d_ws;      // [B, 40] floats

    k_encode<<<B, 256, 0, stream>>>(means, stds, table, feats_ws, coord);
    k_mlp<<<B, 128, 0, stream>>>(feats_ws, viewdirs,
                                 w_d1, b_d1, w_d2, b_d2,
                                 w_v0, b_v0, w_v1, b_v1,
                                 w_rgb, b_rgb, dens, rgb);
}